// Round 25
// baseline (359.844 us; speedup 1.0000x reference)
//
#include <hip/hip_runtime.h>
#include <cstdint>
#include <cstddef>
#include <cmath>

#define BB 256
#define TB 2048
#define NROWS (BB*TB)          // 524288 rows of [64]
#define R1 256                 // rows per k1 block
#define NBLK_K1 (NROWS/R1)     // 2048 blocks
#define NBLK1 4096             // partial granularity: 128-row groups (bit-compat R5..R24)

typedef float f32x4 __attribute__((ext_vector_type(4)));
typedef float f32x2 __attribute__((ext_vector_type(2)));
typedef unsigned long long u64;

// ---- workspace layout (bytes) ----
#define OFF_X      0ull
#define SZ_X       ((size_t)NROWS*64*4)            // 128 MiB raw x_proj [bt][h]
#define OFF_PART   (OFF_X + SZ_X)
#define SZ_PART    ((size_t)128*NBLK1*4)           // 2 MiB partials [ch][4096]
#define OFF_STAT   (OFF_PART + SZ_PART)
#define SZ_STAT    (128*8)                         // f64 col sums / sumsq

// ============ K1: x_proj = kin @ W^T + 128-row-granular col sum/sumsq ============
// R9 kernel verbatim (best profiled: 77-80 us).
__global__ __launch_bounds__(256, 2) void k1_gemm(const float* __restrict__ kin,
                                                  const float* __restrict__ Wsp,
                                                  float* __restrict__ xproj,
                                                  float* __restrict__ partials) {
  __shared__ float4 As[R1 * 16];   // 64 KB: [r][cc ^ ((r>>3)&7)]
  __shared__ f32x4 Wp[32 * 32];    // 16 KB: [p][q ^ ((p>>2)&7)], pair-interleaved
  const int tid = threadIdx.x;
  const int ty = tid >> 3;         // 0..31 -> rows 8*ty..+7
  const int tx = tid & 7;          // col-pairs p = 4*tx..+3 (cols 8*tx..+7)
  const size_t r0 = (size_t)blockIdx.x * R1;

  const f32x4* kin4 = (const f32x4*)(kin + r0 * 64);
  #pragma unroll
  for (int k = 0; k < 16; ++k) {
    int idx = k * 256 + tid;
    int r = idx >> 4, cc = idx & 15;
    f32x4 v = __builtin_nontemporal_load(&kin4[idx]);
    As[r * 16 + (cc ^ ((r >> 3) & 7))] = make_float4(v.x, v.y, v.z, v.w);
  }
  #pragma unroll
  for (int k = 0; k < 4; ++k) {
    int idx = k * 256 + tid;             // 0..1023
    int p = idx >> 5, q = idx & 31;
    float2 w0 = *(const float2*)(Wsp + (2 * p) * 64 + 2 * q);
    float2 w1 = *(const float2*)(Wsp + (2 * p + 1) * 64 + 2 * q);
    Wp[p * 32 + (q ^ ((p >> 2) & 7))] = (f32x4){w0.x, w1.x, w0.y, w1.y};
  }
  __syncthreads();

  f32x2 acc2[8][4];
  #pragma unroll
  for (int i = 0; i < 8; ++i)
    #pragma unroll
    for (int jp = 0; jp < 4; ++jp) acc2[i][jp] = (f32x2){0.f, 0.f};

  #pragma unroll 1
  for (int cc = 0; cc < 16; ++cc) {
    float4 av[8];
    f32x4 q0[4], q1[4];
    #pragma unroll
    for (int i = 0; i < 8; ++i)
      av[i] = As[(8 * ty + i) * 16 + (cc ^ (ty & 7))];
    #pragma unroll
    for (int jp = 0; jp < 4; ++jp) {
      const int p = 4 * tx + jp;
      q0[jp] = Wp[p * 32 + ((2 * cc)     ^ tx)];
      q1[jp] = Wp[p * 32 + ((2 * cc + 1) ^ tx)];
    }
    #pragma unroll
    for (int i = 0; i < 8; ++i) {
      #pragma unroll
      for (int jp = 0; jp < 4; ++jp) {
        acc2[i][jp] = __builtin_elementwise_fma((f32x2){av[i].x, av[i].x}, q0[jp].xy, acc2[i][jp]);
        acc2[i][jp] = __builtin_elementwise_fma((f32x2){av[i].y, av[i].y}, q0[jp].zw, acc2[i][jp]);
        acc2[i][jp] = __builtin_elementwise_fma((f32x2){av[i].z, av[i].z}, q1[jp].xy, acc2[i][jp]);
        acc2[i][jp] = __builtin_elementwise_fma((f32x2){av[i].w, av[i].w}, q1[jp].zw, acc2[i][jp]);
      }
    }
  }

  #pragma unroll
  for (int i = 0; i < 8; ++i) {
    const size_t row = r0 + 8 * ty + i;
    f32x4 lo = {acc2[i][0].x, acc2[i][0].y, acc2[i][1].x, acc2[i][1].y};
    f32x4 hi = {acc2[i][2].x, acc2[i][2].y, acc2[i][3].x, acc2[i][3].y};
    *(f32x4*)(xproj + row * 64 + 8 * tx)     = lo;
    *(f32x4*)(xproj + row * 64 + 8 * tx + 4) = hi;
  }

  __syncthreads();                 // As dead; reuse as stat scratch
  float* Sm = (float*)As;          // [64][33]
  float* Sq = Sm + 64 * 33;
  #pragma unroll
  for (int j = 0; j < 8; ++j) {
    const int col = 8 * tx + j;
    float s = 0.f, q = 0.f;
    #pragma unroll
    for (int i = 0; i < 8; ++i) {
      float v = (j & 1) ? acc2[i][j >> 1].y : acc2[i][j >> 1].x;
      s += v;
      q += v * v;
    }
    Sm[col * 33 + ty] = s;
    Sq[col * 33 + ty] = q;
  }
  __syncthreads();
  if (tid < 64) {
    float s0 = 0.f, q0 = 0.f, s1 = 0.f, q1 = 0.f;
    #pragma unroll
    for (int g = 0; g < 16; ++g)  { s0 += Sm[tid * 33 + g]; q0 += Sq[tid * 33 + g]; }
    #pragma unroll
    for (int g = 16; g < 32; ++g) { s1 += Sm[tid * 33 + g]; q1 += Sq[tid * 33 + g]; }
    const size_t p0 = 2 * (size_t)blockIdx.x;
    partials[(size_t)tid * NBLK1 + p0]            = s0;
    partials[(size_t)tid * NBLK1 + p0 + 1]        = s1;
    partials[(size_t)(64 + tid) * NBLK1 + p0]     = q0;
    partials[(size_t)(64 + tid) * NBLK1 + p0 + 1] = q1;
  }
}

// ============ K2a: deterministic f64 reduction (coalesced rows) ============
__global__ __launch_bounds__(256) void k2a_reduce(const float* __restrict__ partials,
                                                  double* __restrict__ statd) {
  __shared__ double sd[256];
  const int idx = blockIdx.x;              // 0..127
  double acc = 0.0;
  for (int k = threadIdx.x; k < NBLK1; k += 256)
    acc += (double)partials[(size_t)idx * NBLK1 + k];
  sd[threadIdx.x] = acc;
  __syncthreads();
  for (int s = 128; s > 0; s >>= 1) {
    if (threadIdx.x < s) sd[threadIdx.x] += sd[threadIdx.x + s];
    __syncthreads();
  }
  if (threadIdx.x == 0) statd[idx] = sd[0];
}

// ============ K345 v9: speculative-parallel layer-1 scan + transpose + B + C ============
// Exactness: after a spike at step t, mem = xhat_{t+1} (history forgotten).
// Spec pass runs each 128-chunk with "spike-at-entry" init; serial pass
// recomputes from the true init until exact & spec co-spike (states then
// bitwise equal; all per-step ops identical expressions), splices bits.
#define K45_LOAD(BUF, TBASE)                                             \
  { _Pragma("unroll") for (int k_ = 0; k_ < 16; ++k_) {                  \
      f32x4 v = *(const f32x4*)(cr + (TBASE) + 4 * k_);                  \
      BUF[4 * k_] = v.x; BUF[4 * k_ + 1] = v.y;                          \
      BUF[4 * k_ + 2] = v.z; BUF[4 * k_ + 3] = v.w; } }

#define K45_CHUNK(CUR, NXT0)                                  \
  { _Pragma("unroll") for (int i_ = 0; i_ < 64; ++i_) {       \
      bool sp = (mem2 >= th);                                 \
      cnt += sp ? 1u : 0u;                                    \
      float xn = (i_ < 63) ? CUR[(i_ + 1) & 63] : (NXT0);     \
      mem2 = sp ? xn : fmaf(mem2, 0.9f, xn);                  \
    } }

__global__ __launch_bounds__(512) void k345_scan(const float* __restrict__ xproj,
                                                 const double* __restrict__ statd,
                                                 const float* __restrict__ gamma,
                                                 const float* __restrict__ beta,
                                                 const float* __restrict__ Wc,
                                                 const float* __restrict__ lat,
                                                 const float* __restrict__ tda,
                                                 const float* __restrict__ Wtda,
                                                 const float* __restrict__ btda,
                                                 float* __restrict__ out) {
  __shared__ u64 masksT[TB];                  // 16 KB, [chunk64][h] = bits over t
  __shared__ u64 masksL[TB];                  // 16 KB, [t] = bits over h
  __shared__ float specEndL[16 * 64];         // 4 KB, spec end-mem per 128-chunk
  __shared__ float WcL[256];
  __shared__ float latL[16];
  __shared__ float thL[4];
  __shared__ float scL[64];
  __shared__ float shL[64];
  __shared__ float lbuf[4][TB + 4];           // 32.8 KB
  const int tid = threadIdx.x, b = blockIdx.x;
  const int lane = tid & 63;
  const int wv = tid >> 6;                    // 0..7

  if (tid < 256) WcL[tid] = Wc[tid];
  if (tid < 16) latL[tid] = lat[tid];

  // ---- prologue: wave 0 publishes scL/shL; wave 7 thresholds
  if (wv == 0) {
    const int h = lane;
    const double mean = statd[h] / (double)NROWS;
    const double ex2  = statd[64 + h] / (double)NROWS;
    const double var  = ex2 - mean * mean;
    const double scd  = (double)gamma[h] / sqrt(var + 1e-5);
    scL[h] = (float)scd;
    shL[h] = (float)((double)beta[h] - mean * scd);
  } else if (wv == 7 && lane < 4) {
    const int j = lane;
    double acc = (double)btda[j];
    for (int k = 0; k < 50; ++k)
      acc += (double)tda[b * 50 + k] * (double)Wtda[j * 50 + k];
    double sig = 1.0 / (1.0 + exp(-acc));
    thL[j] = (float)(1.0 + 0.5 * sig);
  }
  __syncthreads();

  const float sc = scL[lane], sh = shL[lane];
  const float* xb = xproj + (size_t)b * TB * 64 + lane;   // stride-64 per t

  // ---- speculative pass: wave wv handles 128-chunks {wv, wv+8}
  {
    float sa[64], sb[64];
    #pragma unroll 1
    for (int rep = 0; rep < 2; ++rep) {
      const int cs = wv + rep * 8;            // 0..15
      const int t0 = cs * 128;
      #pragma unroll
      for (int i = 0; i < 64; ++i) sa[i] = xb[(size_t)(t0 + i) * 64];
      #pragma unroll
      for (int i = 0; i < 64; ++i) sb[i] = xb[(size_t)(t0 + 64 + i) * 64];
      const float nxtraw = (cs < 15) ? xb[(size_t)(t0 + 128) * 64] : 0.f;

      float mem = fmaf(sa[0], sc, sh);        // spike-at-entry init
      unsigned l0 = 0u, h0 = 0u, l1 = 0u, h1 = 0u;
      #pragma unroll
      for (int i = 0; i < 64; ++i) {
        bool sp = (mem >= 1.0f);
        if (i < 32) { unsigned t2 = l0 | (1u << i);        l0 = sp ? t2 : l0; }
        else        { unsigned t2 = h0 | (1u << (i - 32)); h0 = sp ? t2 : h0; }
        float rn = (i < 63) ? sa[i + 1] : sb[0];
        float xn = fmaf(rn, sc, sh);
        mem = sp ? xn : fmaf(mem, 0.9f, xn);
      }
      #pragma unroll
      for (int i = 0; i < 64; ++i) {
        bool sp = (mem >= 1.0f);
        if (i < 32) { unsigned t2 = l1 | (1u << i);        l1 = sp ? t2 : l1; }
        else        { unsigned t2 = h1 | (1u << (i - 32)); h1 = sp ? t2 : h1; }
        float rn = (i < 63) ? sb[i + 1] : nxtraw;
        float xn = fmaf(rn, sc, sh);
        mem = sp ? xn : fmaf(mem, 0.9f, xn);
      }
      masksT[(2 * cs) * 64 + lane]     = ((u64)h0 << 32) | l0;
      masksT[(2 * cs + 1) * 64 + lane] = ((u64)h1 << 32) | l1;
      specEndL[cs * 64 + lane] = mem;
    }
  }
  __syncthreads();                            // spec results visible

  // ---- serial merge pass: wave 0 only
  if (wv == 0) {
    float pa[65], pb[65];
    #pragma unroll
    for (int i = 0; i < 65; ++i) pa[i] = xb[(size_t)i * 64];
    float memv = fmaf(pa[0], sc, sh);         // exact state at t=0

    #pragma unroll 1
    for (int c = 0; c < 16; ++c) {
      if (c < 15) {
        #pragma unroll
        for (int i = 0; i < 65; ++i) pb[i] = xb[(size_t)((c + 1) * 128 + i) * 64];
      }
      const u64 mt0 = masksT[(2 * c) * 64 + lane];
      const u64 mt1 = masksT[(2 * c + 1) * 64 + lane];
      const unsigned mt0lo = (unsigned)mt0, mt0hi = (unsigned)(mt0 >> 32);
      const unsigned mt1lo = (unsigned)mt1, mt1hi = (unsigned)(mt1 >> 32);
      bool merged = false;
      int mstep = 128;
      unsigned e0lo = 0u, e0hi = 0u, e1lo = 0u, e1hi = 0u;

      // fast: steps 0..63 in groups of 8 with wave-level early exit
      #pragma unroll 1
      for (int g = 0; g < 8; ++g) {
        #pragma unroll
        for (int k = 0; k < 8; ++k) {
          const int i = g * 8 + k;
          bool act = !merged;
          bool sp = act && (memv >= 1.0f);
          if (i < 32) { unsigned t2 = e0lo | (1u << i);        e0lo = sp ? t2 : e0lo; }
          else        { unsigned t2 = e0hi | (1u << (i - 32)); e0hi = sp ? t2 : e0hi; }
          bool specbit = (((i < 32) ? (mt0lo >> i) : (mt0hi >> (i - 32))) & 1u) != 0u;
          bool co = sp && specbit;
          mstep = co ? i : mstep;
          merged = merged || co;
          float rn = (i < 63) ? pa[i + 1] : pa[64];
          float xn = fmaf(rn, sc, sh);
          float upd = sp ? xn : fmaf(memv, 0.9f, xn);
          memv = (act && !co) ? upd : memv;
        }
        if (__all((int)merged)) break;
      }

      if (!__all((int)merged)) {              // slow path: exact through 127
        #pragma unroll
        for (int j = 0; j < 63; ++j) pa[j] = xb[(size_t)(c * 128 + 65 + j) * 64];
        #pragma unroll
        for (int i = 64; i < 128; ++i) {
          bool act = !merged;
          bool sp = act && (memv >= 1.0f);
          const int i2 = i - 64;
          if (i2 < 32) { unsigned t2 = e1lo | (1u << i2);        e1lo = sp ? t2 : e1lo; }
          else         { unsigned t2 = e1hi | (1u << (i2 - 32)); e1hi = sp ? t2 : e1hi; }
          bool specbit = (((i2 < 32) ? (mt1lo >> i2) : (mt1hi >> (i2 - 32))) & 1u) != 0u;
          bool co = sp && specbit;
          mstep = co ? i : mstep;
          merged = merged || co;
          float rn = (i < 127) ? pa[i - 64] : ((c < 15) ? pb[0] : 0.f);
          float xn = fmaf(rn, sc, sh);
          float upd = sp ? xn : fmaf(memv, 0.9f, xn);
          memv = (act && !co) ? upd : memv;
        }
      }

      // splice per lane
      const u64 ex0 = ((u64)e0hi << 32) | e0lo;
      const u64 ex1 = ((u64)e1hi << 32) | e1lo;
      const bool m1 = merged && (mstep < 64);
      const bool m2 = merged && (mstep >= 64);
      const u64 lm = (2ull << (mstep & 63)) - 1ull;   // (mstep&63)==63 -> all-ones
      const u64 f0 = m1 ? ((ex0 & lm) | (mt0 & ~lm)) : ex0;
      const u64 f1 = m1 ? mt1 : (m2 ? ((ex1 & lm) | (mt1 & ~lm)) : ex1);
      masksT[(2 * c) * 64 + lane]     = f0;
      masksT[(2 * c + 1) * 64 + lane] = f1;
      memv = merged ? specEndL[c * 64 + lane] : memv;

      if (c < 15) {
        #pragma unroll
        for (int i = 0; i < 65; ++i) pa[i] = pb[i];
      }
    }
  }
  __syncthreads();                            // final masksT visible

  // ---- transpose: masksT[chunk64][h] -> masksL[chunk64*64+tb]; 8 waves x 4
  #pragma unroll 1
  for (int cc2 = 0; cc2 < 4; ++cc2) {
    const int chunk = wv * 4 + cc2;
    const u64 m = masksT[chunk * 64 + lane];
    const unsigned mlo = (unsigned)m, mhi = (unsigned)(m >> 32);
    u64 keep = 0ull;
    #pragma unroll
    for (int tb = 0; tb < 64; ++tb) {
      bool sp = (((tb < 32) ? (mlo >> tb) : (mhi >> (tb - 32))) & 1u) != 0u;
      u64 mb = __ballot(sp);
      if (lane == tb) keep = mb;
    }
    masksL[chunk * 64 + lane] = keep;
  }
  __syncthreads();                            // masksL complete & visible

  // ---- phase B: cur2 for all t from LDS masks (identical math)
  #pragma unroll 1
  for (int c = 0; c < 4; ++c) {
    const int t = c * 512 + tid;
    const u64 m = masksL[t];
    const unsigned lo = (unsigned)m, hi = (unsigned)(m >> 32);
    float v0 = 0.f, v1 = 0.f, v2 = 0.f, v3 = 0.f;
    #pragma unroll
    for (int hh = 0; hh < 32; ++hh) {
      const float bit = (float)((lo >> hh) & 1u);
      v0 = fmaf(bit, WcL[hh],       v0);
      v1 = fmaf(bit, WcL[64 + hh],  v1);
      v2 = fmaf(bit, WcL[128 + hh], v2);
      v3 = fmaf(bit, WcL[192 + hh], v3);
    }
    #pragma unroll
    for (int hh = 32; hh < 64; ++hh) {
      const float bit = (float)((hi >> (hh - 32)) & 1u);
      v0 = fmaf(bit, WcL[hh],       v0);
      v1 = fmaf(bit, WcL[64 + hh],  v1);
      v2 = fmaf(bit, WcL[128 + hh], v2);
      v3 = fmaf(bit, WcL[192 + hh], v3);
    }
    { float cx = v0 * latL[0];  cx = fmaf(v1, latL[4],  cx); cx = fmaf(v2, latL[8],  cx); cx = fmaf(v3, latL[12], cx); lbuf[0][t] = cx; }
    { float cx = v0 * latL[1];  cx = fmaf(v1, latL[5],  cx); cx = fmaf(v2, latL[9],  cx); cx = fmaf(v3, latL[13], cx); lbuf[1][t] = cx; }
    { float cx = v0 * latL[2];  cx = fmaf(v1, latL[6],  cx); cx = fmaf(v2, latL[10], cx); cx = fmaf(v3, latL[14], cx); lbuf[2][t] = cx; }
    { float cx = v0 * latL[3];  cx = fmaf(v1, latL[7],  cx); cx = fmaf(v2, latL[11], cx); cx = fmaf(v3, latL[15], cx); lbuf[3][t] = cx; }
  }
  __syncthreads();
  if (tid >= 64) return;

  // ---- phase C: wave 0 scans layer-2 from LDS; lanes mirror 4 chains
  const int j4 = tid & 3;
  const float th = thL[j4];
  const float* cr = lbuf[j4];
  float ca[64], cb[64];

  K45_LOAD(ca, 0)
  float mem2 = ca[0];
  unsigned cnt = 0;

  #pragma unroll 1
  for (int t0 = 0; t0 < TB; t0 += 128) {
    K45_LOAD(cb, t0 + 64)
    K45_CHUNK(ca, cb[0])
    if (t0 + 128 < TB) { K45_LOAD(ca, t0 + 128) }
    K45_CHUNK(cb, ca[0])
  }
  if (tid < 4) out[b * 4 + j4] = (float)cnt;
}

extern "C" void kernel_launch(void* const* d_in, const int* in_sizes, int n_in,
                              void* d_out, int out_size, void* d_ws, size_t ws_size,
                              hipStream_t stream) {
  const float* kin   = (const float*)d_in[0];
  const float* tda   = (const float*)d_in[1];
  const float* Wsp   = (const float*)d_in[2];
  const float* gamma = (const float*)d_in[3];
  const float* beta  = (const float*)d_in[4];
  const float* Wc    = (const float*)d_in[5];
  const float* lat   = (const float*)d_in[6];
  const float* Wtda  = (const float*)d_in[7];
  const float* btda  = (const float*)d_in[8];

  char* ws = (char*)d_ws;
  float*  xproj    = (float*)(ws + OFF_X);
  float*  partials = (float*)(ws + OFF_PART);
  double* statd    = (double*)(ws + OFF_STAT);
  float*  out      = (float*)d_out;

  k1_gemm  <<<dim3(NBLK_K1), dim3(256), 0, stream>>>(kin, Wsp, xproj, partials);
  k2a_reduce<<<dim3(128),  dim3(256), 0, stream>>>(partials, statd);
  k345_scan<<<dim3(BB),    dim3(512), 0, stream>>>(xproj, statd, gamma, beta,
                                                   Wc, lat, tda, Wtda, btda, out);
}

// Round 26
// 146.398 us; speedup vs baseline: 2.4580x; 2.4580x over previous
//
#include <hip/hip_runtime.h>
#include <cstdint>
#include <cstddef>
#include <cmath>

#define BB 256
#define TB 2048
#define NROWS (BB*TB)          // 524288 rows of [64]
#define R1 256                 // rows per k1 block
#define NBLK_K1 (NROWS/R1)     // 2048 blocks
#define NBLK1 4096             // partial granularity: 128-row groups (bit-compat R5..R25)

typedef float f32x4 __attribute__((ext_vector_type(4)));
typedef float f32x2 __attribute__((ext_vector_type(2)));

// ---- workspace layout (bytes) ----
#define OFF_X      0ull
#define SZ_X       ((size_t)NROWS*64*4)            // 128 MiB raw x_proj [bt][h]
#define OFF_PART   (OFF_X + SZ_X)
#define SZ_PART    ((size_t)128*NBLK1*4)           // 2 MiB partials [ch][4096]
#define OFF_STAT   (OFF_PART + SZ_PART)
#define SZ_STAT    (128*8)                         // f64 col sums / sumsq

// async global->LDS, 16 B per lane (HW: LDS dest = wave-uniform base + lane*16)
__device__ __forceinline__ void gll16(const float* g, void* l) {
  __builtin_amdgcn_global_load_lds(
      (const __attribute__((address_space(1))) unsigned int*)g,
      (__attribute__((address_space(3))) unsigned int*)l, 16, 0, 0);
}

// ============ K1: R9 structure, A staged via global_load_lds (no VGPR round trip) ============
// R24 configuration (best timed total: 146.7us). Source-side XOR swizzle,
// linear LDS dest; compute/stats identical to R9 -> bit-exact.
__global__ __launch_bounds__(256, 2) void k1_gemm(const float* __restrict__ kin,
                                                  const float* __restrict__ Wsp,
                                                  float* __restrict__ xproj,
                                                  float* __restrict__ partials) {
  __shared__ float4 As[R1 * 16];   // 64 KB: [r][cc ^ ((r>>3)&7)]
  __shared__ f32x4 Wp[32 * 32];    // 16 KB: [p][q ^ ((p>>2)&7)], pair-interleaved
  const int tid = threadIdx.x;
  const int ty = tid >> 3;         // 0..31 -> rows 8*ty..+7
  const int tx = tid & 7;          // col-pairs p = 4*tx..+3 (cols 8*tx..+7)
  const int lane = tid & 63;
  const int wv4 = tid >> 6;
  const size_t r0 = (size_t)blockIdx.x * R1;

  // ---- stage A via async DMA: slot idx -> r=idx>>4, q=idx&15; source chunk
  //      gq = q ^ ((r>>3)&7) (inverse of read-side swizzle); dest linear.
  {
    const float* gA = kin + r0 * 64;
    #pragma unroll
    for (int k = 0; k < 16; ++k) {
      const int idx0 = k * 256 + wv4 * 64;       // wave-uniform slot base
      const int idx = idx0 + lane;
      const int r = idx >> 4, q = idx & 15;
      const int gq = q ^ ((r >> 3) & 7);
      gll16(gA + (size_t)r * 64 + gq * 4, &As[idx0]);
    }
  }
  // ---- stage W pair-interleaved (regular loads)
  #pragma unroll
  for (int k = 0; k < 4; ++k) {
    int idx = k * 256 + tid;             // 0..1023
    int p = idx >> 5, q = idx & 31;
    float2 w0 = *(const float2*)(Wsp + (2 * p) * 64 + 2 * q);
    float2 w1 = *(const float2*)(Wsp + (2 * p + 1) * 64 + 2 * q);
    Wp[p * 32 + (q ^ ((p >> 2) & 7))] = (f32x4){w0.x, w1.x, w0.y, w1.y};
  }
  __syncthreads();                 // drains DMA + W stores

  f32x2 acc2[8][4];
  #pragma unroll
  for (int i = 0; i < 8; ++i)
    #pragma unroll
    for (int jp = 0; jp < 4; ++jp) acc2[i][jp] = (f32x2){0.f, 0.f};

  #pragma unroll 1
  for (int cc = 0; cc < 16; ++cc) {
    float4 av[8];
    f32x4 q0[4], q1[4];
    #pragma unroll
    for (int i = 0; i < 8; ++i)
      av[i] = As[(8 * ty + i) * 16 + (cc ^ (ty & 7))];
    #pragma unroll
    for (int jp = 0; jp < 4; ++jp) {
      const int p = 4 * tx + jp;
      q0[jp] = Wp[p * 32 + ((2 * cc)     ^ tx)];
      q1[jp] = Wp[p * 32 + ((2 * cc + 1) ^ tx)];
    }
    #pragma unroll
    for (int i = 0; i < 8; ++i) {
      #pragma unroll
      for (int jp = 0; jp < 4; ++jp) {
        acc2[i][jp] = __builtin_elementwise_fma((f32x2){av[i].x, av[i].x}, q0[jp].xy, acc2[i][jp]);
        acc2[i][jp] = __builtin_elementwise_fma((f32x2){av[i].y, av[i].y}, q0[jp].zw, acc2[i][jp]);
        acc2[i][jp] = __builtin_elementwise_fma((f32x2){av[i].z, av[i].z}, q1[jp].xy, acc2[i][jp]);
        acc2[i][jp] = __builtin_elementwise_fma((f32x2){av[i].w, av[i].w}, q1[jp].zw, acc2[i][jp]);
      }
    }
  }

  #pragma unroll
  for (int i = 0; i < 8; ++i) {
    const size_t row = r0 + 8 * ty + i;
    f32x4 lo = {acc2[i][0].x, acc2[i][0].y, acc2[i][1].x, acc2[i][1].y};
    f32x4 hi = {acc2[i][2].x, acc2[i][2].y, acc2[i][3].x, acc2[i][3].y};
    *(f32x4*)(xproj + row * 64 + 8 * tx)     = lo;
    *(f32x4*)(xproj + row * 64 + 8 * tx + 4) = hi;
  }

  __syncthreads();                 // As dead; reuse as stat scratch
  float* Sm = (float*)As;          // [64][33]
  float* Sq = Sm + 64 * 33;
  #pragma unroll
  for (int j = 0; j < 8; ++j) {
    const int col = 8 * tx + j;
    float s = 0.f, q = 0.f;
    #pragma unroll
    for (int i = 0; i < 8; ++i) {  // rows ascending within group
      float v = (j & 1) ? acc2[i][j >> 1].y : acc2[i][j >> 1].x;
      s += v;
      q += v * v;
    }
    Sm[col * 33 + ty] = s;
    Sq[col * 33 + ty] = q;
  }
  __syncthreads();
  if (tid < 64) {
    float s0 = 0.f, q0 = 0.f, s1 = 0.f, q1 = 0.f;
    #pragma unroll
    for (int g = 0; g < 16; ++g)  { s0 += Sm[tid * 33 + g]; q0 += Sq[tid * 33 + g]; }
    #pragma unroll
    for (int g = 16; g < 32; ++g) { s1 += Sm[tid * 33 + g]; q1 += Sq[tid * 33 + g]; }
    const size_t p0 = 2 * (size_t)blockIdx.x;
    partials[(size_t)tid * NBLK1 + p0]            = s0;
    partials[(size_t)tid * NBLK1 + p0 + 1]        = s1;
    partials[(size_t)(64 + tid) * NBLK1 + p0]     = q0;
    partials[(size_t)(64 + tid) * NBLK1 + p0 + 1] = q1;
  }
}

// ============ K2a: deterministic f64 reduction (coalesced rows) ============
__global__ __launch_bounds__(256) void k2a_reduce(const float* __restrict__ partials,
                                                  double* __restrict__ statd) {
  __shared__ double sd[256];
  const int idx = blockIdx.x;              // 0..127
  double acc = 0.0;
  for (int k = threadIdx.x; k < NBLK1; k += 256)
    acc += (double)partials[(size_t)idx * NBLK1 + k];
  sd[threadIdx.x] = acc;
  __syncthreads();
  for (int s = 128; s > 0; s >>= 1) {
    if (threadIdx.x < s) sd[threadIdx.x] += sd[threadIdx.x + s];
    __syncthreads();
  }
  if (threadIdx.x == 0) statd[idx] = sd[0];
}

// ============ K345 v8 (R23/R24, frozen): producer/consumer scan + cur2 + scan2 ============
#define XSW 68
#define K45_LOAD(BUF, TBASE)                                             \
  { _Pragma("unroll") for (int k_ = 0; k_ < 16; ++k_) {                  \
      f32x4 v = *(const f32x4*)(cr + (TBASE) + 4 * k_);                  \
      BUF[4 * k_] = v.x; BUF[4 * k_ + 1] = v.y;                          \
      BUF[4 * k_ + 2] = v.z; BUF[4 * k_ + 3] = v.w; } }

#define K45_CHUNK(CUR, NXT0)                                  \
  { _Pragma("unroll") for (int i_ = 0; i_ < 64; ++i_) {       \
      bool sp = (mem2 >= th);                                 \
      cnt += sp ? 1u : 0u;                                    \
      float xn = (i_ < 63) ? CUR[(i_ + 1) & 63] : (NXT0);     \
      mem2 = sp ? xn : fmaf(mem2, 0.9f, xn);                  \
    } }

#define PROD_WRITE(BF)                                                        \
  { _Pragma("unroll") for (int h2 = 0; h2 < 64; ++h2) {                       \
      float pv;                                                               \
      switch (h2 & 3) {                                                       \
        case 0: pv = pregs[h2 >> 2].x; break;                                 \
        case 1: pv = pregs[h2 >> 2].y; break;                                 \
        case 2: pv = pregs[h2 >> 2].z; break;                                 \
        default: pv = pregs[h2 >> 2].w; break;                                \
      }                                                                       \
      pv = fmaf(pv, scL[h2], shL[h2]);                                        \
      xs[BF][h2][lane] = pv;                                                  \
    } }

#define PROD_ISSUE(C)                                                         \
  { const f32x4* xr_ = (const f32x4*)(xproj + ((size_t)b * TB +               \
                                      (size_t)(C) * 64 + lane) * 64);         \
    _Pragma("unroll") for (int k_ = 0; k_ < 16; ++k_) pregs[k_] = xr_[k_]; }

__global__ __launch_bounds__(256) void k345_scan(const float* __restrict__ xproj,
                                                 const double* __restrict__ statd,
                                                 const float* __restrict__ gamma,
                                                 const float* __restrict__ beta,
                                                 const float* __restrict__ Wc,
                                                 const float* __restrict__ lat,
                                                 const float* __restrict__ tda,
                                                 const float* __restrict__ Wtda,
                                                 const float* __restrict__ btda,
                                                 float* __restrict__ out) {
  __shared__ float xs[4][64][XSW];            // 68 KB chunk ring, [buf][h][t] padded
  __shared__ unsigned long long masksT[TB];   // 16 KB, [chunk][h] = bits over t
  __shared__ unsigned long long masksL[TB];   // 16 KB, [t] = bits over h
  __shared__ float WcL[256];
  __shared__ float latL[16];
  __shared__ float thL[4];
  __shared__ float scL[64];
  __shared__ float shL[64];
  __shared__ float lbuf[4][TB + 4];           // 32.8 KB
  const int tid = threadIdx.x, b = blockIdx.x;
  const int lane = tid & 63;
  const int wv = tid >> 6;

  WcL[tid] = Wc[tid];
  if (tid < 16) latL[tid] = lat[tid];

  float mem = 0.f;
  f32x4 pregs[16];

  if (wv == 0) {
    const int h = lane;
    const double mean = statd[h] / (double)NROWS;
    const double ex2  = statd[64 + h] / (double)NROWS;
    const double var  = ex2 - mean * mean;
    const double scd  = (double)gamma[h] / sqrt(var + 1e-5);
    scL[h] = (float)scd;
    shL[h] = (float)((double)beta[h] - mean * scd);
  } else if (wv == 3) {
    if (lane < 4) {
      const int j = lane;
      double acc = (double)btda[j];
      for (int k = 0; k < 50; ++k)
        acc += (double)tda[b * 50 + k] * (double)Wtda[j * 50 + k];
      double sig = 1.0 / (1.0 + exp(-acc));
      thL[j] = (float)(1.0 + 0.5 * sig);
    }
  } else {
    PROD_ISSUE(wv - 1)          // w1 -> chunk 0, w2 -> chunk 1 (regs only)
  }
  __syncthreads();              // scL/shL + thL visible

  if (wv == 1) { PROD_WRITE(0) PROD_ISSUE(3) }
  else if (wv == 2) { PROD_WRITE(1) }
  else if (wv == 3) { PROD_ISSUE(2) }
  __syncthreads();              // chunks 0,1 visible

  if (wv == 0) {
    mem = xs[0][lane][0];       // xhat at t=0
  }

  #pragma unroll 1
  for (int n = 0; n < 32; ++n) {
    if (n + 2 < 32 && wv == 1 + ((n + 2) % 3)) {
      const int bf = (n + 2) & 3;
      PROD_WRITE(bf)
    }
    if (n + 4 < 32 && wv == 1 + ((n + 1) % 3)) {
      PROD_ISSUE(n + 4)
    }
    if (wv == 0) {
      const int bf = n & 3;
      const f32x4* xrow = (const f32x4*)&xs[bf][lane][0];
      f32x4 av[16];
      #pragma unroll
      for (int i = 0; i < 16; ++i) av[i] = xrow[i];
      const float nxt0 = (n < 31) ? xs[(n + 1) & 3][lane][0] : 0.f;
      unsigned keepLo = 0u, keepHi = 0u;
      #pragma unroll
      for (int i_ = 0; i_ < 64; ++i_) {
        bool sp = (mem >= 1.0f);
        if (i_ < 32) { unsigned t2 = keepLo | (1u << i_);        keepLo = sp ? t2 : keepLo; }
        else         { unsigned t2 = keepHi | (1u << (i_ - 32)); keepHi = sp ? t2 : keepHi; }
        float xn = (i_ < 63) ? av[(i_ + 1) >> 2][(i_ + 1) & 3] : nxt0;
        mem = sp ? xn : fmaf(mem, 0.9f, xn);
      }
      masksT[n * 64 + lane] = ((unsigned long long)keepHi << 32) | keepLo;
    }
    asm volatile("s_waitcnt lgkmcnt(0)" ::: "memory");
    __builtin_amdgcn_sched_barrier(0);
    __builtin_amdgcn_s_barrier();
  }
  __syncthreads();                            // masksT complete & visible

  #pragma unroll 1
  for (int cc2 = 0; cc2 < 8; ++cc2) {
    const int chunk = wv * 8 + cc2;
    const unsigned long long m = masksT[chunk * 64 + lane];
    const unsigned mlo = (unsigned)m, mhi = (unsigned)(m >> 32);
    unsigned long long keep = 0ull;
    #pragma unroll
    for (int tb = 0; tb < 64; ++tb) {
      bool sp = (((tb < 32) ? (mlo >> tb) : (mhi >> (tb - 32))) & 1u) != 0u;
      unsigned long long mb = __ballot(sp);
      if (lane == tb) keep = mb;
    }
    masksL[chunk * 64 + lane] = keep;
  }
  __syncthreads();                            // masksL complete & visible

  #pragma unroll 1
  for (int c = 0; c < 8; ++c) {
    const int t = c * 256 + tid;
    const unsigned long long m = masksL[t];
    const unsigned lo = (unsigned)m, hi = (unsigned)(m >> 32);
    float v0 = 0.f, v1 = 0.f, v2 = 0.f, v3 = 0.f;
    #pragma unroll
    for (int hh = 0; hh < 32; ++hh) {
      const float bit = (float)((lo >> hh) & 1u);
      v0 = fmaf(bit, WcL[hh],       v0);
      v1 = fmaf(bit, WcL[64 + hh],  v1);
      v2 = fmaf(bit, WcL[128 + hh], v2);
      v3 = fmaf(bit, WcL[192 + hh], v3);
    }
    #pragma unroll
    for (int hh = 32; hh < 64; ++hh) {
      const float bit = (float)((hi >> (hh - 32)) & 1u);
      v0 = fmaf(bit, WcL[hh],       v0);
      v1 = fmaf(bit, WcL[64 + hh],  v1);
      v2 = fmaf(bit, WcL[128 + hh], v2);
      v3 = fmaf(bit, WcL[192 + hh], v3);
    }
    { float cx = v0 * latL[0];  cx = fmaf(v1, latL[4],  cx); cx = fmaf(v2, latL[8],  cx); cx = fmaf(v3, latL[12], cx); lbuf[0][t] = cx; }
    { float cx = v0 * latL[1];  cx = fmaf(v1, latL[5],  cx); cx = fmaf(v2, latL[9],  cx); cx = fmaf(v3, latL[13], cx); lbuf[1][t] = cx; }
    { float cx = v0 * latL[2];  cx = fmaf(v1, latL[6],  cx); cx = fmaf(v2, latL[10], cx); cx = fmaf(v3, latL[14], cx); lbuf[2][t] = cx; }
    { float cx = v0 * latL[3];  cx = fmaf(v1, latL[7],  cx); cx = fmaf(v2, latL[11], cx); cx = fmaf(v3, latL[15], cx); lbuf[3][t] = cx; }
  }
  __syncthreads();
  if (tid >= 64) return;

  const int j4 = tid & 3;
  const float th = thL[j4];
  const float* cr = lbuf[j4];
  float ca[64], cb[64];

  K45_LOAD(ca, 0)
  float mem2 = ca[0];
  unsigned cnt = 0;

  #pragma unroll 1
  for (int t0 = 0; t0 < TB; t0 += 128) {
    K45_LOAD(cb, t0 + 64)
    K45_CHUNK(ca, cb[0])
    if (t0 + 128 < TB) { K45_LOAD(ca, t0 + 128) }
    K45_CHUNK(cb, ca[0])
  }
  if (tid < 4) out[b * 4 + j4] = (float)cnt;
}

extern "C" void kernel_launch(void* const* d_in, const int* in_sizes, int n_in,
                              void* d_out, int out_size, void* d_ws, size_t ws_size,
                              hipStream_t stream) {
  const float* kin   = (const float*)d_in[0];
  const float* tda   = (const float*)d_in[1];
  const float* Wsp   = (const float*)d_in[2];
  const float* gamma = (const float*)d_in[3];
  const float* beta  = (const float*)d_in[4];
  const float* Wc    = (const float*)d_in[5];
  const float* lat   = (const float*)d_in[6];
  const float* Wtda  = (const float*)d_in[7];
  const float* btda  = (const float*)d_in[8];

  char* ws = (char*)d_ws;
  float*  xproj    = (float*)(ws + OFF_X);
  float*  partials = (float*)(ws + OFF_PART);
  double* statd    = (double*)(ws + OFF_STAT);
  float*  out      = (float*)d_out;

  k1_gemm  <<<dim3(NBLK_K1), dim3(256), 0, stream>>>(kin, Wsp, xproj, partials);
  k2a_reduce<<<dim3(128),  dim3(256), 0, stream>>>(partials, statd);
  k345_scan<<<dim3(BB),    dim3(256), 0, stream>>>(xproj, statd, gamma, beta,
                                                   Wc, lat, tda, Wtda, btda, out);
}